// Round 16
// baseline (36.725 us; speedup 1.0000x reference)
//
#include <hip/hip_runtime.h>

// FeatIterpNFMLP: trilinear grid interp (16^3 x 8ch) + MLP 8->64->64->16 (leaky 0.01)
// Round 16: KERNEL FISSION of R14 (best known, 28.1 us).
//   Kernel A (interp): 1 thread/point, feat -> bf16-packed 16B/point into d_ws
//     (coalesced). ~50 VGPR -> 8 waves/SIMD: 2x the TLP to hide gather latency,
//     no MFMA state competing. XCD swizzle keeps each XCD on 8 examples (1 MB
//     grids L2-resident) and leaves its 1 MB ws slice warm in its L2.
//   Kernel B (MLP): R14 verbatim, gathers replaced by ONE coalesced 16B ws load.
//     Pure streaming + MFMA (~41 MB -> ~7 us floor), serial chain gone.
//   feat is rounded to bf16 by the SAME cvt_pk in both versions -> output is
//   bit-identical to R14 (absmax 2.441406e-4). d_ws guarded: < 8 MB -> R14 path.
// Session rules: d_ws only with size guard; no forced VGPR caps.

typedef __attribute__((ext_vector_type(8)))  short short8;
typedef __attribute__((ext_vector_type(16))) float f32x16;
typedef __attribute__((ext_vector_type(4)))  int   int4v;

static __device__ __forceinline__ unsigned cvt_pk_bf16(float lo, float hi) {
    unsigned r;
    asm("v_cvt_pk_bf16_f32 %0, %1, %2" : "=v"(r) : "v"(lo), "v"(hi));
    return r;
}
// v_permlane32_swap_b32: swaps low-32-lane half of a with high-32-lane half of b.
static __device__ __forceinline__ void permswap(unsigned &a, unsigned &b) {
    asm("v_permlane32_swap_b32 %0, %1" : "+v"(a), "+v"(b));
}
static __device__ __forceinline__ short8 as_s8(int4v v) {
    return __builtin_bit_cast(short8, v);
}

// ---------------- Kernel A: interp -> bf16-packed feat in ws -------------------
__global__ __launch_bounds__(256) void interp_kernel(
    const int* __restrict__ idx,
    const float* __restrict__ x,
    const float* __restrict__ emb,
    int4v* __restrict__ ws)
{
    const int bid = blockIdx.x;                              // 2048 blocks
    const int swz = (bid & 7) * 256 + (bid >> 3);            // bijective: 2048%8==0
    const long p = (long)swz * 256 + threadIdx.x;            // point id
    const int  b = swz >> 5;                                 // 32 blocks / example

    const float* __restrict__ g = emb + ((long)idx[b] << 15);

    const float x0 = x[p * 3 + 0];
    const float x1 = x[p * 3 + 1];
    const float x2 = x[p * 3 + 2];

    // No masks/clamps: x = -0.5 + k*2^-23 => x+0.5 exact => ix in [0,14], in-bounds.
    const float lx = (x0 + 0.5f) * 15.0f;
    const float ly = (x1 + 0.5f) * 15.0f;
    const float lz = (x2 + 0.5f) * 15.0f;
    const float fx = floorf(lx), fy = floorf(ly), fz = floorf(lz);
    const float wx1 = lx - fx, wy1 = ly - fy, wz1 = lz - fz;
    const float wx0 = 1.0f - wx1, wy0 = 1.0f - wy1, wz0 = 1.0f - wz1;
    const int ix = (int)fx, iy = (int)fy, iz = (int)fz;
    const int vbase = ((iz * 16) + iy) * 16 + ix;

    float feat[8];
    #pragma unroll
    for (int c = 0; c < 8; ++c) feat[c] = 0.0f;
    #pragma unroll
    for (int dz = 0; dz < 2; ++dz) {
        const float wz = dz ? wz1 : wz0;
        #pragma unroll
        for (int dy = 0; dy < 2; ++dy) {
            const float wzy = wz * (dy ? wy1 : wy0);
            #pragma unroll
            for (int dx = 0; dx < 2; ++dx) {
                const float w = wzy * (dx ? wx1 : wx0);
                const float4* v = (const float4*)(g + (long)(vbase + dz * 256 + dy * 16 + dx) * 8);
                const float4 v0 = v[0];
                const float4 v1 = v[1];
                feat[0] += w * v0.x; feat[1] += w * v0.y;
                feat[2] += w * v0.z; feat[3] += w * v0.w;
                feat[4] += w * v1.x; feat[5] += w * v1.y;
                feat[6] += w * v1.z; feat[7] += w * v1.w;
            }
        }
    }

    int4v f;                                   // SAME cvt_pk rounding as fused path
    f[0] = (int)cvt_pk_bf16(feat[0], feat[1]);
    f[1] = (int)cvt_pk_bf16(feat[2], feat[3]);
    f[2] = (int)cvt_pk_bf16(feat[4], feat[5]);
    f[3] = (int)cvt_pk_bf16(feat[6], feat[7]);
    ws[p] = f;                                 // coalesced 16B store
}

// leaky-relu one ct's accum pair in place, repack as next-layer B-fragments:
// bfr[kt], k = kt*16 + 8*half + {0..7}.  acc: col(point)=l31, row(j)=(r&3)+8*(r>>2)+4*half.
static __device__ __forceinline__ void relu_pack_ct(f32x16 acc[2], int4v bfr[4]) {
    #pragma unroll
    for (int rt = 0; rt < 2; ++rt)
        #pragma unroll
        for (int r = 0; r < 16; ++r) {
            float a = acc[rt][r];
            acc[rt][r] = fmaxf(a, 0.01f * a);
        }
    #pragma unroll
    for (int kt = 0; kt < 4; ++kt) {
        const int rs = kt >> 1;
        const int base = (kt & 1) * 8;
        unsigned pa0 = cvt_pk_bf16(acc[rs][base + 0], acc[rs][base + 1]);
        unsigned pa1 = cvt_pk_bf16(acc[rs][base + 2], acc[rs][base + 3]);
        unsigned pb0 = cvt_pk_bf16(acc[rs][base + 4], acc[rs][base + 5]);
        unsigned pb1 = cvt_pk_bf16(acc[rs][base + 6], acc[rs][base + 7]);
        permswap(pa0, pb0);
        permswap(pa1, pb1);
        bfr[kt][0] = (int)pa0;
        bfr[kt][1] = (int)pa1;
        bfr[kt][2] = (int)pb0;
        bfr[kt][3] = (int)pb1;
    }
}

// Shared device body for the MLP given bf0 fragments (used by both kernels).
// FEAT_FROM_WS: true -> fv supplied; false -> caller computed bf0 already.

// ---------------- Kernel B: MLP from packed feat ------------------------------
template <bool FUSED>
__global__ __launch_bounds__(512) void mlp_kernel(
    const int* __restrict__ idx,
    const float* __restrict__ x,
    const float* __restrict__ emb,
    const float* __restrict__ W0, const float* __restrict__ b0,
    const float* __restrict__ W1, const float* __restrict__ b1,
    const float* __restrict__ Wout, const float* __restrict__ bout,
    const int4v* __restrict__ ws,
    float* __restrict__ out)
{
    __shared__ int4v frag_lds[17 * 64];        // 17 KB

    const int tid  = threadIdx.x;
    const int warp = tid >> 6;                 // 0..7
    const int lane = tid & 63;
    const int half = lane >> 5;
    const int l31  = lane & 31;

    const int bid = blockIdx.x;
    const int swz = (bid & 7) * 128 + (bid >> 3);            // bijective on [0,1024)
    const int group = swz * 8 + warp;                        // 8192 groups
    const long pbase = (long)group * 64;
    const int  b  = group >> 7;

    // ---- feat source ----
    int4v fv;                 // packed bf16 feat pairs (ws path)
    float x0, x1, x2;
    const float* __restrict__ g = emb + ((long)idx[b] << 15);
    const long p = pbase + lane;
    if (FUSED) {
        x0 = x[p * 3 + 0]; x1 = x[p * 3 + 1]; x2 = x[p * 3 + 2];
    } else {
        fv = ws[p];                            // coalesced 16B, L2-warm from kernel A
    }

    // ---- cooperative prolog: 17 fragment families over 8 warps ----
    for (int fid = warp; fid < 17; fid += 8) {
        int4v f;
        if (fid < 2) {
            const int j = fid * 32 + l31;
            if (half == 0) {
                #pragma unroll
                for (int m = 0; m < 4; ++m)
                    f[m] = (int)cvt_pk_bf16(W0[(2 * m) * 64 + j], W0[(2 * m + 1) * 64 + j]);
            } else {
                f[0] = (int)cvt_pk_bf16(b0[j], 0.0f);
                f[1] = 0; f[2] = 0; f[3] = 0;
            }
        } else if (fid < 12) {
            const int t = fid - 2;
            const int rt = t / 5, kt = t % 5;
            const int j = rt * 32 + l31;
            if (kt < 4) {
                #pragma unroll
                for (int m = 0; m < 4; ++m) {
                    const int k = kt * 16 + half * 8 + 2 * m;
                    f[m] = (int)cvt_pk_bf16(W1[k * 64 + j], W1[(k + 1) * 64 + j]);
                }
            } else {
                f[0] = half ? 0 : (int)cvt_pk_bf16(b1[j], 0.0f);
                f[1] = 0; f[2] = 0; f[3] = 0;
            }
        } else {
            const int kt = fid - 12;
            const int jo = l31 < 15 ? l31 : 15;
            if (kt < 4) {
                #pragma unroll
                for (int m = 0; m < 4; ++m) {
                    const int k = kt * 16 + half * 8 + 2 * m;
                    f[m] = (int)cvt_pk_bf16(Wout[k * 16 + jo], Wout[(k + 1) * 16 + jo]);
                }
            } else {
                f[0] = half ? 0 : (int)cvt_pk_bf16(bout[jo], 0.0f);
                f[1] = 0; f[2] = 0; f[3] = 0;
            }
        }
        frag_lds[fid * 64 + lane] = f;
    }

    // ---- FUSED path computes feat while prolog loads are in flight ----
    if (FUSED) {
        const float lx = (x0 + 0.5f) * 15.0f;
        const float ly = (x1 + 0.5f) * 15.0f;
        const float lz = (x2 + 0.5f) * 15.0f;
        const float fx = floorf(lx), fy = floorf(ly), fz = floorf(lz);
        const float wx1 = lx - fx, wy1 = ly - fy, wz1 = lz - fz;
        const float wx0 = 1.0f - wx1, wy0 = 1.0f - wy1, wz0 = 1.0f - wz1;
        const int ix = (int)fx, iy = (int)fy, iz = (int)fz;
        const int vbase = ((iz * 16) + iy) * 16 + ix;

        float feat[8];
        #pragma unroll
        for (int c = 0; c < 8; ++c) feat[c] = 0.0f;
        #pragma unroll
        for (int dz = 0; dz < 2; ++dz) {
            const float wz = dz ? wz1 : wz0;
            #pragma unroll
            for (int dy = 0; dy < 2; ++dy) {
                const float wzy = wz * (dy ? wy1 : wy0);
                #pragma unroll
                for (int dx = 0; dx < 2; ++dx) {
                    const float w = wzy * (dx ? wx1 : wx0);
                    const float4* v = (const float4*)(g + (long)(vbase + dz * 256 + dy * 16 + dx) * 8);
                    const float4 v0 = v[0];
                    const float4 v1 = v[1];
                    feat[0] += w * v0.x; feat[1] += w * v0.y;
                    feat[2] += w * v0.z; feat[3] += w * v0.w;
                    feat[4] += w * v1.x; feat[5] += w * v1.y;
                    feat[6] += w * v1.z; feat[7] += w * v1.w;
                }
            }
        }
        fv[0] = (int)cvt_pk_bf16(feat[0], feat[1]);
        fv[1] = (int)cvt_pk_bf16(feat[2], feat[3]);
        fv[2] = (int)cvt_pk_bf16(feat[4], feat[5]);
        fv[3] = (int)cvt_pk_bf16(feat[6], feat[7]);
    }

    __syncthreads();   // fragments ready

    // ---- fv -> layer-0 B-fragments; k=8 row seeded to 1.0 (bias row) ----
    int4v bf0[2];
    #pragma unroll
    for (int m = 0; m < 4; ++m) {
        unsigned a = (unsigned)fv[m];
        unsigned z = (m == 0) ? 0x00003f80u : 0u;
        permswap(a, z);
        bf0[0][m] = (int)a;
        bf0[1][m] = (int)z;
    }

    int4v b1x;
    b1x[0] = half ? 0 : 0x00003f80;
    b1x[1] = 0; b1x[2] = 0; b1x[3] = 0;

    f32x16 zc;
    #pragma unroll
    for (int i = 0; i < 16; ++i) zc[i] = 0.0f;

    #pragma unroll
    for (int ct = 0; ct < 2; ++ct) {
        f32x16 acc0[2];
        #pragma unroll
        for (int rt = 0; rt < 2; ++rt) {
            const int4v wf = frag_lds[rt * 64 + lane];
            acc0[rt] = __builtin_amdgcn_mfma_f32_32x32x16_bf16(
                as_s8(wf), as_s8(bf0[ct]), zc, 0, 0, 0);
        }

        int4v b1f[4];
        relu_pack_ct(acc0, b1f);

        f32x16 acc1[2];
        #pragma unroll
        for (int rt = 0; rt < 2; ++rt) {
            f32x16 a = zc;
            #pragma unroll
            for (int kt = 0; kt < 4; ++kt) {
                const int4v wf = frag_lds[(2 + rt * 5 + kt) * 64 + lane];
                a = __builtin_amdgcn_mfma_f32_32x32x16_bf16(
                    as_s8(wf), as_s8(b1f[kt]), a, 0, 0, 0);
            }
            const int4v wb = frag_lds[(2 + rt * 5 + 4) * 64 + lane];
            acc1[rt] = __builtin_amdgcn_mfma_f32_32x32x16_bf16(
                as_s8(wb), as_s8(b1x), a, 0, 0, 0);
        }

        int4v b2f[4];
        relu_pack_ct(acc1, b2f);

        f32x16 a = zc;
        #pragma unroll
        for (int kt = 0; kt < 4; ++kt) {
            const int4v wf = frag_lds[(12 + kt) * 64 + lane];
            a = __builtin_amdgcn_mfma_f32_32x32x16_bf16(
                as_s8(wf), as_s8(b2f[kt]), a, 0, 0, 0);
        }
        const int4v wb = frag_lds[16 * 64 + lane];
        a = __builtin_amdgcn_mfma_f32_32x32x16_bf16(
            as_s8(wb), as_s8(b1x), a, 0, 0, 0);

        float* o = out + (pbase + ct * 32 + l31) * 16;
        *(float4*)(o + half * 4)     = make_float4(a[0], a[1], a[2], a[3]);
        *(float4*)(o + 8 + half * 4) = make_float4(a[4], a[5], a[6], a[7]);
    }
}

extern "C" void kernel_launch(void* const* d_in, const int* in_sizes, int n_in,
                              void* d_out, int out_size, void* d_ws, size_t ws_size,
                              hipStream_t stream) {
    const int*   idx  = (const int*)  d_in[0];
    const float* x    = (const float*)d_in[1];
    const float* emb  = (const float*)d_in[2];
    const float* W0   = (const float*)d_in[3];
    const float* b0   = (const float*)d_in[4];
    const float* W1   = (const float*)d_in[5];
    const float* b1   = (const float*)d_in[6];
    const float* Wout = (const float*)d_in[7];
    const float* bout = (const float*)d_in[8];
    float* out = (float*)d_out;

    const size_t need = 524288ull * 16;        // 8 MB packed feat
    if (ws_size >= need && d_ws != nullptr) {
        int4v* ws = (int4v*)d_ws;
        interp_kernel<<<2048, 256, 0, stream>>>(idx, x, emb, ws);
        mlp_kernel<false><<<1024, 512, 0, stream>>>(idx, x, emb, W0, b0, W1, b1,
                                                    Wout, bout, ws, out);
    } else {
        // R14 fallback (best known fused path, 28.1 us)
        mlp_kernel<true><<<1024, 512, 0, stream>>>(idx, x, emb, W0, b0, W1, b1,
                                                   Wout, bout, (const int4v*)nullptr, out);
    }
}

// Round 17
// 28.452 us; speedup vs baseline: 1.2908x; 1.2908x over previous
//
#include <hip/hip_runtime.h>

// FeatIterpNFMLP: trilinear grid interp (16^3 x 8ch) + MLP 8->64->64->16 (leaky 0.01)
// Round 17: R14 (best, 28.1 us) + block persistence: 512 blocks x 2 virtual
// blocks each; cooperative prolog + barrier run ONCE per block (R13 measured
// prolog-amortize-x2 = +1.7 us; this is one more doubling). Set-1's x preloaded
// up front (+3 VGPR only; no gather prefetch per R7 lesson). Virtual blocks
// v0 = xcd*128 + 2*slot, v1 = v0+1 are always in the same example (v1 odd),
// same XCD chunk as R14 (1 MB grids/XCD L2-resident). Numerics bit-identical.
// Session rules: no d_ws, no forced VGPR caps.

typedef __attribute__((ext_vector_type(8)))  short short8;
typedef __attribute__((ext_vector_type(16))) float f32x16;
typedef __attribute__((ext_vector_type(4)))  int   int4v;

static __device__ __forceinline__ unsigned cvt_pk_bf16(float lo, float hi) {
    unsigned r;
    asm("v_cvt_pk_bf16_f32 %0, %1, %2" : "=v"(r) : "v"(lo), "v"(hi));
    return r;
}
// v_permlane32_swap_b32: swaps low-32-lane half of a with high-32-lane half of b.
static __device__ __forceinline__ void permswap(unsigned &a, unsigned &b) {
    asm("v_permlane32_swap_b32 %0, %1" : "+v"(a), "+v"(b));
}
static __device__ __forceinline__ short8 as_s8(int4v v) {
    return __builtin_bit_cast(short8, v);
}

// leaky-relu one ct's accum pair in place, repack as next-layer B-fragments:
// bfr[kt], k = kt*16 + 8*half + {0..7}.  acc: col(point)=l31, row(j)=(r&3)+8*(r>>2)+4*half.
static __device__ __forceinline__ void relu_pack_ct(f32x16 acc[2], int4v bfr[4]) {
    #pragma unroll
    for (int rt = 0; rt < 2; ++rt)
        #pragma unroll
        for (int r = 0; r < 16; ++r) {
            float a = acc[rt][r];
            acc[rt][r] = fmaxf(a, 0.01f * a);
        }
    #pragma unroll
    for (int kt = 0; kt < 4; ++kt) {
        const int rs = kt >> 1;
        const int base = (kt & 1) * 8;
        unsigned pa0 = cvt_pk_bf16(acc[rs][base + 0], acc[rs][base + 1]);
        unsigned pa1 = cvt_pk_bf16(acc[rs][base + 2], acc[rs][base + 3]);
        unsigned pb0 = cvt_pk_bf16(acc[rs][base + 4], acc[rs][base + 5]);
        unsigned pb1 = cvt_pk_bf16(acc[rs][base + 6], acc[rs][base + 7]);
        permswap(pa0, pb0);
        permswap(pa1, pb1);
        bfr[kt][0] = (int)pa0;
        bfr[kt][1] = (int)pa1;
        bfr[kt][2] = (int)pb0;
        bfr[kt][3] = (int)pb1;
    }
}

// One 64-point group: interp -> MLP -> store. Weights/biases come from frag_lds.
static __device__ __forceinline__ void process_group(
    float x0, float x1, float x2, long pbase,
    const float* __restrict__ g,
    const int4v* __restrict__ frag_lds,
    int half, int l31, int lane,
    const int4v& b1x, const f32x16& zc,
    float* __restrict__ out)
{
    // ---- trilinear interp (no masks/clamps: x = -0.5 + k*2^-23 => in-bounds) ----
    const float lx = (x0 + 0.5f) * 15.0f;
    const float ly = (x1 + 0.5f) * 15.0f;
    const float lz = (x2 + 0.5f) * 15.0f;
    const float fx = floorf(lx), fy = floorf(ly), fz = floorf(lz);
    const float wx1 = lx - fx, wy1 = ly - fy, wz1 = lz - fz;
    const float wx0 = 1.0f - wx1, wy0 = 1.0f - wy1, wz0 = 1.0f - wz1;
    const int ix = (int)fx, iy = (int)fy, iz = (int)fz;
    const int vbase = ((iz * 16) + iy) * 16 + ix;

    float feat[8];
    #pragma unroll
    for (int c = 0; c < 8; ++c) feat[c] = 0.0f;
    #pragma unroll
    for (int dz = 0; dz < 2; ++dz) {
        const float wz = dz ? wz1 : wz0;
        #pragma unroll
        for (int dy = 0; dy < 2; ++dy) {
            const float wzy = wz * (dy ? wy1 : wy0);
            #pragma unroll
            for (int dx = 0; dx < 2; ++dx) {
                const float w = wzy * (dx ? wx1 : wx0);
                const float4* v = (const float4*)(g + (long)(vbase + dz * 256 + dy * 16 + dx) * 8);
                const float4 v0 = v[0];
                const float4 v1 = v[1];
                feat[0] += w * v0.x; feat[1] += w * v0.y;
                feat[2] += w * v0.z; feat[3] += w * v0.w;
                feat[4] += w * v1.x; feat[5] += w * v1.y;
                feat[6] += w * v1.z; feat[7] += w * v1.w;
            }
        }
    }

    // ---- feat -> layer-0 B-fragments; k=8 row seeded to 1.0 (bias row) ----
    int4v bf0[2];
    #pragma unroll
    for (int m = 0; m < 4; ++m) {
        unsigned a = cvt_pk_bf16(feat[2 * m], feat[2 * m + 1]);
        unsigned z = (m == 0) ? 0x00003f80u : 0u;
        permswap(a, z);
        bf0[0][m] = (int)a;
        bf0[1][m] = (int)z;
    }

    // ================= ct-sequential MLP (32 points per pass) =================
    #pragma unroll
    for (int ct = 0; ct < 2; ++ct) {
        f32x16 acc0[2];
        #pragma unroll
        for (int rt = 0; rt < 2; ++rt) {
            const int4v wf = frag_lds[rt * 64 + lane];
            acc0[rt] = __builtin_amdgcn_mfma_f32_32x32x16_bf16(
                as_s8(wf), as_s8(bf0[ct]), zc, 0, 0, 0);
        }

        int4v b1f[4];
        relu_pack_ct(acc0, b1f);

        f32x16 acc1[2];
        #pragma unroll
        for (int rt = 0; rt < 2; ++rt) {
            f32x16 a = zc;
            #pragma unroll
            for (int kt = 0; kt < 4; ++kt) {
                const int4v wf = frag_lds[(2 + rt * 5 + kt) * 64 + lane];
                a = __builtin_amdgcn_mfma_f32_32x32x16_bf16(
                    as_s8(wf), as_s8(b1f[kt]), a, 0, 0, 0);
            }
            const int4v wb = frag_lds[(2 + rt * 5 + 4) * 64 + lane];
            acc1[rt] = __builtin_amdgcn_mfma_f32_32x32x16_bf16(
                as_s8(wb), as_s8(b1x), a, 0, 0, 0);
        }

        int4v b2f[4];
        relu_pack_ct(acc1, b2f);

        f32x16 a = zc;
        #pragma unroll
        for (int kt = 0; kt < 4; ++kt) {
            const int4v wf = frag_lds[(12 + kt) * 64 + lane];
            a = __builtin_amdgcn_mfma_f32_32x32x16_bf16(
                as_s8(wf), as_s8(b2f[kt]), a, 0, 0, 0);
        }
        const int4v wb = frag_lds[16 * 64 + lane];
        a = __builtin_amdgcn_mfma_f32_32x32x16_bf16(
            as_s8(wb), as_s8(b1x), a, 0, 0, 0);

        // j = (r&3) + 8*(r>>2) + 4*half ; point = pbase + ct*32 + l31
        float* o = out + (pbase + ct * 32 + l31) * 16;
        *(float4*)(o + half * 4)     = make_float4(a[0], a[1], a[2], a[3]);
        *(float4*)(o + 8 + half * 4) = make_float4(a[4], a[5], a[6], a[7]);
    }
}

__global__ __launch_bounds__(512) void featmlp_mfma(
    const int* __restrict__ idx,
    const float* __restrict__ x,
    const float* __restrict__ emb,
    const float* __restrict__ W0, const float* __restrict__ b0,
    const float* __restrict__ W1, const float* __restrict__ b1,
    const float* __restrict__ Wout, const float* __restrict__ bout,
    float* __restrict__ out)
{
    // fid 0-1: w0f[rt] (b0 folded at k=8) ; fid 2+rt*5+kt: w1f[rt][kt] kt=0..4
    // (b1 folded at k=64) ; fid 12+kt: wof[kt] kt=0..4 (bout folded at k=64)
    __shared__ int4v frag_lds[17 * 64];        // 17 KB, 16B lane stride

    const int tid  = threadIdx.x;
    const int warp = tid >> 6;                 // 0..7
    const int lane = tid & 63;
    const int half = lane >> 5;
    const int l31  = lane & 31;

    // 512 blocks; XCD (bid&7) serves slots (bid>>3) in [0,64): virtual blocks
    // v0 = xcd*128 + 2*slot and v1 = v0+1 (same XCD chunk as R14, same example).
    const int bid  = blockIdx.x;
    const int v0   = (bid & 7) * 128 + (bid >> 3) * 2;
    const int g0   = v0 * 8 + warp;                          // set-0 group
    const long pbase0 = (long)g0 * 64;
    const long pbase1 = pbase0 + 512;                        // set-1 group = g0 + 8
    const int  b   = v0 >> 4;                                // example (shared)

    const float* __restrict__ g = emb + ((long)idx[b] << 15);

    // ---- x loads for BOTH sets issued first (6 scalars; hides under prolog) ----
    const long p0 = pbase0 + lane;
    const long p1 = pbase1 + lane;
    const float xa0 = x[p0 * 3 + 0], xa1 = x[p0 * 3 + 1], xa2 = x[p0 * 3 + 2];
    const float xb0 = x[p1 * 3 + 0], xb1 = x[p1 * 3 + 1], xb2 = x[p1 * 3 + 2];

    // ---- cooperative prolog: 17 fragment families over 8 warps (ONCE per block) ----
    // A[row=j][k] = W[k][j]; lane holds row j = rt*32 + l31, k = kt*16 + half*8 + 2m+{0,1}
    for (int fid = warp; fid < 17; fid += 8) {
        int4v f;
        if (fid < 2) {                         // w0f rt=fid; b0 folded at k=8
            const int j = fid * 32 + l31;
            if (half == 0) {
                #pragma unroll
                for (int m = 0; m < 4; ++m)
                    f[m] = (int)cvt_pk_bf16(W0[(2 * m) * 64 + j], W0[(2 * m + 1) * 64 + j]);
            } else {
                f[0] = (int)cvt_pk_bf16(b0[j], 0.0f);       // k=8 -> bias row
                f[1] = 0; f[2] = 0; f[3] = 0;
            }
        } else if (fid < 12) {                 // w1f rt=(fid-2)/5, kt=(fid-2)%5
            const int t = fid - 2;
            const int rt = t / 5, kt = t % 5;
            const int j = rt * 32 + l31;
            if (kt < 4) {
                #pragma unroll
                for (int m = 0; m < 4; ++m) {
                    const int k = kt * 16 + half * 8 + 2 * m;
                    f[m] = (int)cvt_pk_bf16(W1[k * 64 + j], W1[(k + 1) * 64 + j]);
                }
            } else {                           // kt=4: k=64 -> b1 row
                f[0] = half ? 0 : (int)cvt_pk_bf16(b1[j], 0.0f);
                f[1] = 0; f[2] = 0; f[3] = 0;
            }
        } else {                               // wof kt=fid-12 (rows j>=16 unused, clamp)
            const int kt = fid - 12;
            const int jo = l31 < 15 ? l31 : 15;
            if (kt < 4) {
                #pragma unroll
                for (int m = 0; m < 4; ++m) {
                    const int k = kt * 16 + half * 8 + 2 * m;
                    f[m] = (int)cvt_pk_bf16(Wout[k * 16 + jo], Wout[(k + 1) * 16 + jo]);
                }
            } else {                           // kt=4: k=64 -> bout row
                f[0] = half ? 0 : (int)cvt_pk_bf16(bout[jo], 0.0f);
                f[1] = 0; f[2] = 0; f[3] = 0;
            }
        }
        frag_lds[fid * 64 + lane] = f;
    }

    __syncthreads();   // fragments ready (written once; no later writes)

    // constant B-fragment for the K=80 bias tile (row 64 == 1.0): lanes<32, m0 low.
    int4v b1x;
    b1x[0] = half ? 0 : 0x00003f80;
    b1x[1] = 0; b1x[2] = 0; b1x[3] = 0;

    f32x16 zc;                                 // shared zero C-operand
    #pragma unroll
    for (int i = 0; i < 16; ++i) zc[i] = 0.0f;

    // ---- set 0, then set 1 (x already resident; prolog amortized over both) ----
    process_group(xa0, xa1, xa2, pbase0, g, frag_lds, half, l31, lane, b1x, zc, out);
    process_group(xb0, xb1, xb2, pbase1, g, frag_lds, half, l31, lane, b1x, zc, out);
}

extern "C" void kernel_launch(void* const* d_in, const int* in_sizes, int n_in,
                              void* d_out, int out_size, void* d_ws, size_t ws_size,
                              hipStream_t stream) {
    const int*   idx  = (const int*)  d_in[0];
    const float* x    = (const float*)d_in[1];
    const float* emb  = (const float*)d_in[2];
    const float* W0   = (const float*)d_in[3];
    const float* b0   = (const float*)d_in[4];
    const float* W1   = (const float*)d_in[5];
    const float* b1   = (const float*)d_in[6];
    const float* Wout = (const float*)d_in[7];
    const float* bout = (const float*)d_in[8];
    float* out = (float*)d_out;

    // 8192 groups / (8 warps x 2 sets) = 512 blocks of 512 threads
    featmlp_mfma<<<512, 512, 0, stream>>>(idx, x, emb, W0, b0, W1, b1,
                                          Wout, bout, out);
}

// Round 18
// 27.777 us; speedup vs baseline: 1.3221x; 1.0243x over previous
//
#include <hip/hip_runtime.h>

// FeatIterpNFMLP: trilinear grid interp (16^3 x 8ch) + MLP 8->64->64->16 (leaky 0.01)
// Round 18: R14 base (best, 28.1 us) + static K-permutation (jmap):
//   W1/Wout A-fragments are built with K-axis rows permuted to match the NATURAL
//   in-lane acc->pack stream, so relu_pack needs ZERO cross-lane ops
//   (-32 v_permlane32_swap per group; pack = fmax + 16 straight cvt_pk).
//   Each K=16 tile still sums the same 16 j's (kt0={0..15}, kt1={16..31}, ...) ->
//   only intra-MFMA summation order changes (<=LSB; budget 1.1e-3 >> 2.4e-4).
//   Layer-0 bf0 permswap kept (real data movement for ct=1 + bias seed).
// Session rules: no d_ws, no forced VGPR caps; XCD swizzle (R14-proven).

typedef __attribute__((ext_vector_type(8)))  short short8;
typedef __attribute__((ext_vector_type(16))) float f32x16;
typedef __attribute__((ext_vector_type(4)))  int   int4v;

static __device__ __forceinline__ unsigned cvt_pk_bf16(float lo, float hi) {
    unsigned r;
    asm("v_cvt_pk_bf16_f32 %0, %1, %2" : "=v"(r) : "v"(lo), "v"(hi));
    return r;
}
// v_permlane32_swap_b32: swaps low-32-lane half of a with high-32-lane half of b.
static __device__ __forceinline__ void permswap(unsigned &a, unsigned &b) {
    asm("v_permlane32_swap_b32 %0, %1" : "+v"(a), "+v"(b));
}
static __device__ __forceinline__ short8 as_s8(int4v v) {
    return __builtin_bit_cast(short8, v);
}

// K-axis permutation: B-slot k holds acc value j = jmap(k).
// Derivation: acc row j = (r&3) + 8*(r>>2) + 4*half; pack stream pair index
// linear = kt*4 + m; rs = linear>>3; pair = linear&7; r = 2*pair + e.
static __device__ __forceinline__ int jmap(int k) {
    const int kt = k >> 4, kk = k & 15, h = kk >> 3, s = kk & 7;
    const int m = s >> 1, e = s & 1;
    const int linear = kt * 4 + m;
    const int rs = linear >> 3, pair = linear & 7;
    const int r = 2 * pair + e;
    return (r & 3) + 8 * (r >> 2) + 4 * h + 32 * rs;
}

// leaky-relu one ct's accum pair, pack IN-LANE in stream order (no cross-lane):
// bfr[kt][m] <- pack(acc[rs][2*pair], acc[rs][2*pair+1]), linear = kt*4+m.
static __device__ __forceinline__ void relu_pack_ct(f32x16 acc[2], int4v bfr[4]) {
    #pragma unroll
    for (int rs = 0; rs < 2; ++rs)
        #pragma unroll
        for (int r = 0; r < 16; ++r) {
            float a = acc[rs][r];
            acc[rs][r] = fmaxf(a, 0.01f * a);
        }
    #pragma unroll
    for (int linear = 0; linear < 16; ++linear) {
        const int rs = linear >> 3, pair = linear & 7;
        const int kt = linear >> 2, m = linear & 3;
        bfr[kt][m] = (int)cvt_pk_bf16(acc[rs][2 * pair], acc[rs][2 * pair + 1]);
    }
}

__global__ __launch_bounds__(512) void featmlp_mfma(
    const int* __restrict__ idx,
    const float* __restrict__ x,
    const float* __restrict__ emb,
    const float* __restrict__ W0, const float* __restrict__ b0,
    const float* __restrict__ W1, const float* __restrict__ b1,
    const float* __restrict__ Wout, const float* __restrict__ bout,
    float* __restrict__ out)
{
    // fid 0-1: w0f[rt] (b0 folded at k=8, identity K order) ;
    // fid 2+rt*5+kt: w1f[rt][kt] kt=0..4 (kt<4 jmap-permuted; kt=4 bias row k=64) ;
    // fid 12+kt: wof[kt] kt=0..4 (same scheme)
    __shared__ int4v frag_lds[17 * 64];        // 17 KB, 16B lane stride

    const int tid  = threadIdx.x;
    const int warp = tid >> 6;                 // 0..7
    const int lane = tid & 63;
    const int half = lane >> 5;
    const int l31  = lane & 31;

    // XCD-chunked swizzle (R14): bijective on [0,1024).
    const int bid = blockIdx.x;
    const int swz = (bid & 7) * 128 + (bid >> 3);
    const int group = swz * 8 + warp;                        // 8192 groups
    const long pbase = (long)group * 64;
    const int  b  = group >> 7;                              // 128 groups / example

    const float* __restrict__ g = emb + ((long)idx[b] << 15);

    // ---- x loads issued first; latency hides under prolog ----
    const long p = pbase + lane;
    const float x0 = x[p * 3 + 0];
    const float x1 = x[p * 3 + 1];
    const float x2 = x[p * 3 + 2];

    // ---- cooperative prolog: 17 fragment families over 8 warps (<=3 each) ----
    // A[row=j2][k]: lane holds row j2 = rt*32 + l31, k = kt*16 + half*8 + 2m+{0,1}
    for (int fid = warp; fid < 17; fid += 8) {
        int4v f;
        if (fid < 2) {                         // w0f rt=fid; b0 folded at k=8 (identity K)
            const int j = fid * 32 + l31;
            if (half == 0) {
                #pragma unroll
                for (int m = 0; m < 4; ++m)
                    f[m] = (int)cvt_pk_bf16(W0[(2 * m) * 64 + j], W0[(2 * m + 1) * 64 + j]);
            } else {
                f[0] = (int)cvt_pk_bf16(b0[j], 0.0f);       // k=8 -> bias row
                f[1] = 0; f[2] = 0; f[3] = 0;
            }
        } else if (fid < 12) {                 // w1f rt=(fid-2)/5, kt=(fid-2)%5
            const int t = fid - 2;
            const int rt = t / 5, kt = t % 5;
            const int j = rt * 32 + l31;
            if (kt < 4) {
                #pragma unroll
                for (int m = 0; m < 4; ++m) {
                    const int k = kt * 16 + half * 8 + 2 * m;
                    f[m] = (int)cvt_pk_bf16(W1[jmap(k) * 64 + j],
                                            W1[jmap(k + 1) * 64 + j]);
                }
            } else {                           // kt=4: k=64 -> b1 row
                f[0] = half ? 0 : (int)cvt_pk_bf16(b1[j], 0.0f);
                f[1] = 0; f[2] = 0; f[3] = 0;
            }
        } else {                               // wof kt=fid-12 (rows j>=16 unused, clamp)
            const int kt = fid - 12;
            const int jo = l31 < 15 ? l31 : 15;
            if (kt < 4) {
                #pragma unroll
                for (int m = 0; m < 4; ++m) {
                    const int k = kt * 16 + half * 8 + 2 * m;
                    f[m] = (int)cvt_pk_bf16(Wout[jmap(k) * 16 + jo],
                                            Wout[jmap(k + 1) * 16 + jo]);
                }
            } else {                           // kt=4: k=64 -> bout row
                f[0] = half ? 0 : (int)cvt_pk_bf16(bout[jo], 0.0f);
                f[1] = 0; f[2] = 0; f[3] = 0;
            }
        }
        frag_lds[fid * 64 + lane] = f;
    }

    __syncthreads();   // fragments ready (written once; no later writes)

    // ---- trilinear interp (no masks/clamps: x = -0.5 + k*2^-23 => in-bounds) ----
    const float lx = (x0 + 0.5f) * 15.0f;
    const float ly = (x1 + 0.5f) * 15.0f;
    const float lz = (x2 + 0.5f) * 15.0f;
    const float fx = floorf(lx), fy = floorf(ly), fz = floorf(lz);
    const float wx1 = lx - fx, wy1 = ly - fy, wz1 = lz - fz;
    const float wx0 = 1.0f - wx1, wy0 = 1.0f - wy1, wz0 = 1.0f - wz1;
    const int ix = (int)fx, iy = (int)fy, iz = (int)fz;
    const int vbase = ((iz * 16) + iy) * 16 + ix;

    float feat[8];
    #pragma unroll
    for (int c = 0; c < 8; ++c) feat[c] = 0.0f;
    #pragma unroll
    for (int dz = 0; dz < 2; ++dz) {
        const float wz = dz ? wz1 : wz0;
        #pragma unroll
        for (int dy = 0; dy < 2; ++dy) {
            const float wzy = wz * (dy ? wy1 : wy0);
            #pragma unroll
            for (int dx = 0; dx < 2; ++dx) {
                const float w = wzy * (dx ? wx1 : wx0);
                const float4* v = (const float4*)(g + (long)(vbase + dz * 256 + dy * 16 + dx) * 8);
                const float4 v0 = v[0];
                const float4 v1 = v[1];
                feat[0] += w * v0.x; feat[1] += w * v0.y;
                feat[2] += w * v0.z; feat[3] += w * v0.w;
                feat[4] += w * v1.x; feat[5] += w * v1.y;
                feat[6] += w * v1.z; feat[7] += w * v1.w;
            }
        }
    }

    // ---- feat -> layer-0 B-fragments; k=8 row seeded to 1.0 (bias row) ----
    // (permswap kept here: ct=1 needs upper-lane feats -> real data movement)
    int4v bf0[2];
    #pragma unroll
    for (int m = 0; m < 4; ++m) {
        unsigned a = cvt_pk_bf16(feat[2 * m], feat[2 * m + 1]);
        unsigned z = (m == 0) ? 0x00003f80u : 0u;    // bf16 1.0 at k=8, col-broadcast
        permswap(a, z);
        bf0[0][m] = (int)a;
        bf0[1][m] = (int)z;
    }

    // constant B-fragment for the K=80 bias tile (row 64 == 1.0): lanes<32, m0 low.
    int4v b1x;
    b1x[0] = half ? 0 : 0x00003f80;
    b1x[1] = 0; b1x[2] = 0; b1x[3] = 0;

    f32x16 zc;                                        // shared zero C-operand
    #pragma unroll
    for (int i = 0; i < 16; ++i) zc[i] = 0.0f;

    // ================= ct-sequential MLP (32 points per pass) =================
    #pragma unroll
    for (int ct = 0; ct < 2; ++ct) {
        // ---- layer 0 ----
        f32x16 acc0[2];
        #pragma unroll
        for (int rt = 0; rt < 2; ++rt) {
            const int4v wf = frag_lds[rt * 64 + lane];
            acc0[rt] = __builtin_amdgcn_mfma_f32_32x32x16_bf16(
                as_s8(wf), as_s8(bf0[ct]), zc, 0, 0, 0);
        }

        int4v b1f[4];
        relu_pack_ct(acc0, b1f);        // in-lane pack; W1 fragments are jmap'd

        // ---- layer 1 (K=80: 4 jmap'd data tiles + bias tile) ----
        f32x16 acc1[2];
        #pragma unroll
        for (int rt = 0; rt < 2; ++rt) {
            f32x16 a = zc;
            #pragma unroll
            for (int kt = 0; kt < 4; ++kt) {
                const int4v wf = frag_lds[(2 + rt * 5 + kt) * 64 + lane];
                a = __builtin_amdgcn_mfma_f32_32x32x16_bf16(
                    as_s8(wf), as_s8(b1f[kt]), a, 0, 0, 0);
            }
            const int4v wb = frag_lds[(2 + rt * 5 + 4) * 64 + lane];
            acc1[rt] = __builtin_amdgcn_mfma_f32_32x32x16_bf16(
                as_s8(wb), as_s8(b1x), a, 0, 0, 0);
        }

        int4v b2f[4];
        relu_pack_ct(acc1, b2f);        // in-lane pack; Wout fragments are jmap'd

        // ---- layer 2 (K=80; rows j<16 valid) ----
        f32x16 a = zc;
        #pragma unroll
        for (int kt = 0; kt < 4; ++kt) {
            const int4v wf = frag_lds[(12 + kt) * 64 + lane];
            a = __builtin_amdgcn_mfma_f32_32x32x16_bf16(
                as_s8(wf), as_s8(b2f[kt]), a, 0, 0, 0);
        }
        const int4v wb = frag_lds[16 * 64 + lane];
        a = __builtin_amdgcn_mfma_f32_32x32x16_bf16(
            as_s8(wb), as_s8(b1x), a, 0, 0, 0);

        // j = (r&3) + 8*(r>>2) + 4*half ; point = pbase + ct*32 + l31
        float* o = out + (pbase + ct * 32 + l31) * 16;
        *(float4*)(o + half * 4)     = make_float4(a[0], a[1], a[2], a[3]);
        *(float4*)(o + 8 + half * 4) = make_float4(a[4], a[5], a[6], a[7]);
    }
}

extern "C" void kernel_launch(void* const* d_in, const int* in_sizes, int n_in,
                              void* d_out, int out_size, void* d_ws, size_t ws_size,
                              hipStream_t stream) {
    const int*   idx  = (const int*)  d_in[0];
    const float* x    = (const float*)d_in[1];
    const float* emb  = (const float*)d_in[2];
    const float* W0   = (const float*)d_in[3];
    const float* b0   = (const float*)d_in[4];
    const float* W1   = (const float*)d_in[5];
    const float* b1   = (const float*)d_in[6];
    const float* Wout = (const float*)d_in[7];
    const float* bout = (const float*)d_in[8];
    float* out = (float*)d_out;

    // 8192 groups / 8 per block = 1024 blocks of 512 threads
    featmlp_mfma<<<1024, 512, 0, stream>>>(idx, x, emb, W0, b0, W1, b1,
                                           Wout, bout, out);
}